// Round 3
// baseline (143.164 us; speedup 1.0000x reference)
//
#include <hip/hip_runtime.h>
#include <math.h>

#define NX 2048
#define NV 1024
static constexpr float DXf   = 1.0f / 2048.0f;       // 4.8828125e-4
static constexpr float DVf   = 12.0f / 1024.0f;      // 0.01171875
static constexpr float DTf   = 0.001f;
static constexpr float INV_DX = 2048.0f;
static constexpr float INV_DV = 1024.0f / 12.0f;     // 85.3333...

__device__ __forceinline__ float minmod_f(float a, float b) {
    return (a * b > 0.0f) ? (a > 0.0f ? fminf(a, b) : fmaxf(a, b)) : 0.0f;
}

// fast reciprocal: v_rcp_f32 + 1 Newton step (~2e-7 rel err; system is diag-dominant)
__device__ __forceinline__ float frcp(float x) {
    float r = __builtin_amdgcn_rcpf(x);
    return r * (2.0f - x * r);
}

// MUSCL minmod upwind rhs at (i,j); also returns f0 by ref.
__device__ __forceinline__ float rhs_at(const float* __restrict__ g, int i, int j,
                                        float Ec, float& f0out) {
    int idx = i * NV + j;
    int im1 = (((i - 1) & (NX - 1)) * NV) + j;
    int im2 = (((i - 2) & (NX - 1)) * NV) + j;
    int ip1 = (((i + 1) & (NX - 1)) * NV) + j;
    int ip2 = (((i + 2) & (NX - 1)) * NV) + j;

    float f0  = g[idx];
    float fm1 = g[im1], fm2 = g[im2], fp1 = g[ip1], fp2 = g[ip2];

    float v = DVf * ((float)j + 0.5f) - 6.0f;
    float dm1 = fm1 - fm2, d0 = f0 - fm1, dp1 = fp1 - f0, dp2 = fp2 - fp1;
    float sm1 = minmod_f(dm1, d0);
    float s0  = minmod_f(d0, dp1);
    float sp1 = minmod_f(dp1, dp2);
    float PhiM, PhiP;
    if (v > 0.0f) {
        PhiM = (fm1 + 0.5f * sm1) * v;
        PhiP = (f0  + 0.5f * s0 ) * v;
    } else {
        PhiM = (f0  - 0.5f * s0 ) * v;
        PhiP = (fp1 - 0.5f * sp1) * v;
    }
    float vdfdx = (PhiP - PhiM) * INV_DX;

    float gm1 = (j >= 1)      ? g[idx - 1] : 0.0f;
    float gm2 = (j >= 2)      ? g[idx - 2] : 0.0f;
    float gp1 = (j <= NV - 2) ? g[idx + 1] : 0.0f;
    float gp2 = (j <= NV - 3) ? g[idx + 2] : 0.0f;
    float em1 = gm1 - gm2, e0 = f0 - gm1, ep1 = gp1 - f0, ep2 = gp2 - gp1;
    float tm1 = minmod_f(em1, e0);
    float t0  = minmod_f(e0, ep1);
    float tp1 = minmod_f(ep1, ep2);
    float GM, GP;
    if (Ec > 0.0f) {
        GM = (gm1 + 0.5f * tm1) * Ec;
        GP = (f0  + 0.5f * t0 ) * Ec;
    } else {
        GM = (f0  - 0.5f * t0 ) * Ec;
        GP = (gp1 - 0.5f * tp1) * Ec;
    }
    float Edfdv = (GP - GM) * INV_DV;

    f0out = f0;
    return -vdfdx - Edfdv;
}

// se[i] = sum_j fe[i,j]; si[i] = sum_j fi[i,j]
__global__ __launch_bounds__(256) void moments_kernel(const float* __restrict__ fe,
                                                      const float* __restrict__ fi,
                                                      float* __restrict__ se,
                                                      float* __restrict__ si) {
    int i = blockIdx.x;
    int t = threadIdx.x;
    const float* re = fe + (size_t)i * NV;
    const float* ri = fi + (size_t)i * NV;
    float a = 0.0f, b = 0.0f;
    for (int j = t; j < NV; j += 256) { a += re[j]; b += ri[j]; }
    __shared__ float s1[256], s2[256];
    s1[t] = a; s2[t] = b;
    __syncthreads();
    for (int off = 128; off > 0; off >>= 1) {
        if (t < off) { s1[t] += s1[t + off]; s2[t] += s2[t + off]; }
        __syncthreads();
    }
    if (t == 0) { se[i] = s1[0]; si[i] = s2[0]; }
}

// rho = DV*(si-se); E = cumsum(rho)*DX; E -= mean(E). Single block, 1024 threads.
__global__ __launch_bounds__(1024) void poisson_kernel(const float* __restrict__ se,
                                                       const float* __restrict__ si,
                                                       float* __restrict__ E) {
    __shared__ float p[1024];
    __shared__ float red[1024];
    int t = threadIdx.x;
    float r0 = DVf * (si[2 * t]     - se[2 * t]);
    float r1 = DVf * (si[2 * t + 1] - se[2 * t + 1]);
    p[t] = r0 + r1;
    __syncthreads();
    for (int off = 1; off < 1024; off <<= 1) {
        float v = p[t];
        float add = (t >= off) ? p[t - off] : 0.0f;
        __syncthreads();
        p[t] = v + add;
        __syncthreads();
    }
    float Pexcl = (t > 0) ? p[t - 1] : 0.0f;
    float S0 = Pexcl + r0;
    float S1 = p[t];
    red[t] = S0 + S1;
    __syncthreads();
    for (int off = 512; off > 0; off >>= 1) {
        if (t < off) red[t] += red[t + off];
        __syncthreads();
    }
    float meanS = red[0] * (1.0f / (float)NX);
    E[2 * t]     = DXf * (S0 - meanS);
    E[2 * t + 1] = DXf * (S1 - meanS);
}

// Stage 1: f1 = f + dt*rhs(f); also writes row sums se1/si1. One block per (row, sp).
__global__ __launch_bounds__(256) void stage1_kernel(const float* __restrict__ fe,
                                                     const float* __restrict__ fi,
                                                     const float* __restrict__ E,
                                                     float* __restrict__ fe1,
                                                     float* __restrict__ fi1,
                                                     float* __restrict__ se1,
                                                     float* __restrict__ si1) {
    int i  = blockIdx.x;
    int sp = blockIdx.y;
    const float* g = sp ? fi : fe;
    float* out = sp ? fi1 : fe1;
    float zoa = sp ? (1.0f / 1836.0f) : -1.0f;
    float Ec = zoa * E[i];
    int t = threadIdx.x;

    float acc = 0.0f;
    #pragma unroll
    for (int r = 0; r < 4; ++r) {
        int j = r * 256 + t;
        float f0;
        float rr = rhs_at(g, i, j, Ec, f0);
        float o = f0 + DTf * rr;
        out[i * NV + j] = o;
        acc += o;
    }
    __shared__ float s1[256];
    s1[t] = acc;
    __syncthreads();
    for (int off = 128; off > 0; off >>= 1) {
        if (t < off) s1[t] += s1[t + off];
        __syncthreads();
    }
    if (t == 0) { (sp ? si1 : se1)[i] = s1[0]; }
}

// Stage 2 + implicit LBO collide, fused. One block (256 thr) per (row, sp).
// o = 0.5*f + 0.5*f1 + 0.5*dt*rhs(f1)  -> padded LDS -> wave-0 SPIKE tridiag
// solve (16 elems/lane, lane-0 serial 64-interface chain) -> coalesced store.
__global__ __launch_bounds__(256) void stage2_collide_kernel(const float* __restrict__ fe,
                                                             const float* __restrict__ fi,
                                                             const float* __restrict__ fe1,
                                                             const float* __restrict__ fi1,
                                                             const float* __restrict__ E,
                                                             float* __restrict__ out) {
    const float Tdv2   = 1.0f / (DVf * DVf);
    const float inv2dv = 0.5f / DVf;

    int i  = blockIdx.x;
    int sp = blockIdx.y;
    const float* h = sp ? fi : fe;
    const float* g = sp ? fi1 : fe1;
    float* orow = out + ((size_t)sp * NX + i) * NV;
    float zoa = sp ? (1.0f / 1836.0f) : -1.0f;
    float lam = sp ? 0.1f : 1.0f;
    float Ec = zoa * E[i];
    int t = threadIdx.x;
    int lane = t & 63;
    int wave = t >> 6;

    __shared__ float lds_f[NV + NV / 16];   // padded: addr(j) = j + (j>>4)
    __shared__ float ifc[64][6];

    #pragma unroll
    for (int r = 0; r < 4; ++r) {
        int j = r * 256 + t;
        float f0;
        float rr = rhs_at(g, i, j, Ec, f0);
        float o = 0.5f * h[i * NV + j] + 0.5f * f0 + (0.5f * DTf) * rr;
        lds_f[j + (j >> 4)] = o;
    }
    __syncthreads();

    // row-constant collision coefficients
    float xi = DXf * ((float)i + 0.5f) - 0.5f;
    float nu = 1.0f / (1.0f + 0.5f * (expf(60.0f * xi - 20.0f) + expf(-60.0f * xi - 20.0f)));
    float K = DTf * nu * lam;
    float b = 1.0f + 2.0f * K * Tdv2;

    float Dv[16], Av[16], Cv[16];
    if (wave == 0) {
        int j0 = lane * 16;
        int base = 17 * lane;      // padded address of j0 (contiguous 16)
        // forward elimination (normalized): x_r = Dv_r - Av_r*x_left - Cv_r*x_{r+1}
        #pragma unroll
        for (int r = 0; r < 16; ++r) {
            int j = j0 + r;
            float d = lds_f[base + r];
            float a = (j == 0)      ? 0.0f : -K * (Tdv2 - (DVf * ((float)j - 0.5f) - 6.0f) * inv2dv);
            float c = (j == NV - 1) ? 0.0f : -K * (Tdv2 + (DVf * ((float)j + 1.5f) - 6.0f) * inv2dv);
            if (r == 0) {
                float e = frcp(b);
                Dv[0] = e * d;
                Av[0] = e * a;
                Cv[0] = e * c;
            } else {
                float e = frcp(b - a * Cv[r - 1]);
                Dv[r] = e * (d - a * Dv[r - 1]);
                Av[r] = -e * a * Av[r - 1];
                Cv[r] = e * c;
            }
        }
        // backward: x_r = Dv_r - Av_r*x_left - Cv_r*x_right
        #pragma unroll
        for (int r = 14; r >= 0; --r) {
            Dv[r] = Dv[r] - Cv[r] * Dv[r + 1];
            Av[r] = Av[r] - Cv[r] * Av[r + 1];
            Cv[r] = -Cv[r] * Cv[r + 1];
        }
        ifc[lane][0] = Av[0];
        ifc[lane][1] = Cv[0];
        ifc[lane][2] = Dv[0];
        ifc[lane][3] = Av[15];
        ifc[lane][4] = Cv[15];
        ifc[lane][5] = Dv[15];
    }
    __syncthreads();

    if (wave == 0 && lane == 0) {
        // forward over interface chain: z_{t-1} = g2p - qp*y_t
        float qp = 0.0f, g2p = 0.0f;
        for (int u = 0; u < 64; ++u) {
            float A0 = ifc[u][0], C0 = ifc[u][1], D0 = ifc[u][2];
            float A1 = ifc[u][3], C1 = ifc[u][4], D1 = ifc[u][5];
            float e  = frcp(1.0f - A0 * qp);
            float p  = e * C0;
            float g1 = e * (D0 - A0 * g2p);
            float q  = A1 * qp * p + C1;
            float g2 = D1 - A1 * (g2p - qp * g1);
            ifc[u][0] = p;
            ifc[u][1] = q;
            ifc[u][2] = g1;
            ifc[u][3] = g2;
            qp = q; g2p = g2;
        }
        // backward: y_u = g1 - p*y_{u+1}, z_u = g2 - q*y_{u+1}
        float yn = 0.0f;
        for (int u = 63; u >= 0; --u) {
            float p  = ifc[u][0], q  = ifc[u][1];
            float g1 = ifc[u][2], g2 = ifc[u][3];
            float y = g1 - p * yn;
            float z = g2 - q * yn;
            ifc[u][4] = y;
            ifc[u][5] = z;
            yn = y;
        }
    }
    __syncthreads();

    if (wave == 0) {
        float zl = (lane == 0)  ? 0.0f : ifc[lane - 1][5];
        float yr = (lane == 63) ? 0.0f : ifc[lane + 1][4];
        int base = 17 * lane;
        #pragma unroll
        for (int r = 0; r < 16; ++r) {
            lds_f[base + r] = Dv[r] - Av[r] * zl - Cv[r] * yr;
        }
    }
    __syncthreads();

    // coalesced float4 store: thread t owns j = 4t..4t+3 (same 16-group -> contiguous in LDS)
    {
        int j = 4 * t;
        int a = j + (j >> 4);
        float4 o;
        o.x = lds_f[a];
        o.y = lds_f[a + 1];
        o.z = lds_f[a + 2];
        o.w = lds_f[a + 3];
        *(float4*)(orow + j) = o;
    }
}

extern "C" void kernel_launch(void* const* d_in, const int* in_sizes, int n_in,
                              void* d_out, int out_size, void* d_ws, size_t ws_size,
                              hipStream_t stream) {
    const float* fe = (const float*)d_in[0];
    const float* fi = (const float*)d_in[1];
    float* out = (float*)d_out;
    const size_t P = (size_t)NX * NV;

    float* fe1 = (float*)d_ws;
    float* fi1 = fe1 + P;
    float* se  = fi1 + P;
    float* si  = se + NX;
    float* E   = si + NX;
    float* se1 = E + NX;
    float* si1 = se1 + NX;
    float* E1  = si1 + NX;

    dim3 rgrid(NX, 2);

    // ---- RK stage 1: f1 = f + dt*rhs(f), fused row-moment outputs ----
    moments_kernel<<<NX, 256, 0, stream>>>(fe, fi, se, si);
    poisson_kernel<<<1, 1024, 0, stream>>>(se, si, E);
    stage1_kernel<<<rgrid, 256, 0, stream>>>(fe, fi, E, fe1, fi1, se1, si1);

    // ---- RK stage 2 + implicit LBO collide (fused) ----
    poisson_kernel<<<1, 1024, 0, stream>>>(se1, si1, E1);
    stage2_collide_kernel<<<rgrid, 256, 0, stream>>>(fe, fi, fe1, fi1, E1, out);
}

// Round 4
// 116.096 us; speedup vs baseline: 1.2332x; 1.2332x over previous
//
#include <hip/hip_runtime.h>
#include <math.h>

#define NX 2048
#define NV 1024
static constexpr float DXf   = 1.0f / 2048.0f;
static constexpr float DVf   = 12.0f / 1024.0f;
static constexpr float DTf   = 0.001f;
static constexpr float INV_DX = 2048.0f;
static constexpr float INV_DV = 1024.0f / 12.0f;

__device__ __forceinline__ float minmod_f(float a, float b) {
    return (a * b > 0.0f) ? (a > 0.0f ? fminf(a, b) : fmaxf(a, b)) : 0.0f;
}

__device__ __forceinline__ float frcp(float x) {
    float r = __builtin_amdgcn_rcpf(x);
    return r * (2.0f - x * r);
}

// Vectorized MUSCL rhs for 4 contiguous cells j0..j0+3 (j0 % 4 == 0).
// f0v out: center values; rv out: rhs values.
__device__ __forceinline__ void rhs4(const float* __restrict__ g, int i, int j0, float Ec,
                                     float4& f0v, float4& rv) {
    const float* rowc = g + i * NV;
    const float* rm1  = g + (((i - 1) & (NX - 1)) * NV);
    const float* rm2  = g + (((i - 2) & (NX - 1)) * NV);
    const float* rp1  = g + (((i + 1) & (NX - 1)) * NV);
    const float* rp2  = g + (((i + 2) & (NX - 1)) * NV);

    float4 c   = *(const float4*)(rowc + j0);
    float4 xm1 = *(const float4*)(rm1 + j0);
    float4 xm2 = *(const float4*)(rm2 + j0);
    float4 xp1 = *(const float4*)(rp1 + j0);
    float4 xp2 = *(const float4*)(rp2 + j0);
    float4 lm = make_float4(0.f, 0.f, 0.f, 0.f);
    float4 rp = make_float4(0.f, 0.f, 0.f, 0.f);
    if (j0 >= 4)      lm = *(const float4*)(rowc + j0 - 4);
    if (j0 <= NV - 8) rp = *(const float4*)(rowc + j0 + 4);

    // v-neighborhood ring: vals[k] = f(i, j0-2+k), zeros beyond row ends
    float vals[8] = {lm.z, lm.w, c.x, c.y, c.z, c.w, rp.x, rp.y};
    const float* cc   = (const float*)&c;
    const float* am1  = (const float*)&xm1;
    const float* am2  = (const float*)&xm2;
    const float* ap1  = (const float*)&xp1;
    const float* ap2  = (const float*)&xp2;
    float* f0o = (float*)&f0v;
    float* ro  = (float*)&rv;

    #pragma unroll
    for (int k = 0; k < 4; ++k) {
        float f0  = cc[k];
        float fm1 = am1[k], fm2 = am2[k], fp1 = ap1[k], fp2 = ap2[k];

        float v = DVf * ((float)(j0 + k) + 0.5f) - 6.0f;
        float dm1 = fm1 - fm2, d0 = f0 - fm1, dp1 = fp1 - f0, dp2 = fp2 - fp1;
        float sm1 = minmod_f(dm1, d0);
        float s0  = minmod_f(d0, dp1);
        float sp1 = minmod_f(dp1, dp2);
        float PhiM, PhiP;
        if (v > 0.0f) {
            PhiM = (fm1 + 0.5f * sm1) * v;
            PhiP = (f0  + 0.5f * s0 ) * v;
        } else {
            PhiM = (f0  - 0.5f * s0 ) * v;
            PhiP = (fp1 - 0.5f * sp1) * v;
        }
        float vdfdx = (PhiP - PhiM) * INV_DX;

        float gm2 = vals[k], gm1 = vals[k + 1], gp1 = vals[k + 3], gp2 = vals[k + 4];
        float em1 = gm1 - gm2, e0 = f0 - gm1, ep1 = gp1 - f0, ep2 = gp2 - gp1;
        float tm1 = minmod_f(em1, e0);
        float t0  = minmod_f(e0, ep1);
        float tp1 = minmod_f(ep1, ep2);
        float GM, GP;
        if (Ec > 0.0f) {
            GM = (gm1 + 0.5f * tm1) * Ec;
            GP = (f0  + 0.5f * t0 ) * Ec;
        } else {
            GM = (f0  - 0.5f * t0 ) * Ec;
            GP = (gp1 - 0.5f * tp1) * Ec;
        }
        float Edfdv = (GP - GM) * INV_DV;

        f0o[k] = f0;
        ro[k]  = -vdfdx - Edfdv;
    }
}

// block-wide sum of one float per thread (256 threads), result on thread 0
__device__ __forceinline__ float block_sum256(float x, float* sred) {
    #pragma unroll
    for (int off = 32; off > 0; off >>= 1) x += __shfl_down(x, off, 64);
    int lane = threadIdx.x & 63, wave = threadIdx.x >> 6;
    if (lane == 0) sred[wave] = x;
    __syncthreads();
    float r = 0.0f;
    if (threadIdx.x == 0) r = sred[0] + sred[1] + sred[2] + sred[3];
    return r;
}

// se[i] = sum_j fe[i,j]; si[i] = sum_j fi[i,j]
__global__ __launch_bounds__(256) void moments_kernel(const float* __restrict__ fe,
                                                      const float* __restrict__ fi,
                                                      float* __restrict__ se,
                                                      float* __restrict__ si) {
    int i = blockIdx.x;
    int t = threadIdx.x;
    float4 a4 = *(const float4*)(fe + (size_t)i * NV + 4 * t);
    float4 b4 = *(const float4*)(fi + (size_t)i * NV + 4 * t);
    float a = a4.x + a4.y + a4.z + a4.w;
    float b = b4.x + b4.y + b4.z + b4.w;
    __shared__ float r1[4], r2[4];
    #pragma unroll
    for (int off = 32; off > 0; off >>= 1) {
        a += __shfl_down(a, off, 64);
        b += __shfl_down(b, off, 64);
    }
    int lane = t & 63, wave = t >> 6;
    if (lane == 0) { r1[wave] = a; r2[wave] = b; }
    __syncthreads();
    if (t == 0) {
        se[i] = r1[0] + r1[1] + r1[2] + r1[3];
        si[i] = r2[0] + r2[1] + r2[2] + r2[3];
    }
}

// rho = DV*(si-se); E = cumsum(rho)*DX; E -= mean(E). Single block, 1024 threads.
__global__ __launch_bounds__(1024) void poisson_kernel(const float* __restrict__ se,
                                                       const float* __restrict__ si,
                                                       float* __restrict__ E) {
    __shared__ float p[1024];
    __shared__ float red[1024];
    int t = threadIdx.x;
    float r0 = DVf * (si[2 * t]     - se[2 * t]);
    float r1 = DVf * (si[2 * t + 1] - se[2 * t + 1]);
    p[t] = r0 + r1;
    __syncthreads();
    for (int off = 1; off < 1024; off <<= 1) {
        float v = p[t];
        float add = (t >= off) ? p[t - off] : 0.0f;
        __syncthreads();
        p[t] = v + add;
        __syncthreads();
    }
    float Pexcl = (t > 0) ? p[t - 1] : 0.0f;
    float S0 = Pexcl + r0;
    float S1 = p[t];
    red[t] = S0 + S1;
    __syncthreads();
    for (int off = 512; off > 0; off >>= 1) {
        if (t < off) red[t] += red[t + off];
        __syncthreads();
    }
    float meanS = red[0] * (1.0f / (float)NX);
    E[2 * t]     = DXf * (S0 - meanS);
    E[2 * t + 1] = DXf * (S1 - meanS);
}

// Stage 1: f1 = f + dt*rhs(f); writes row sums. One block per (row, sp), float4/thread.
__global__ __launch_bounds__(256) void stage1_kernel(const float* __restrict__ fe,
                                                     const float* __restrict__ fi,
                                                     const float* __restrict__ E,
                                                     float* __restrict__ fe1,
                                                     float* __restrict__ fi1,
                                                     float* __restrict__ se1,
                                                     float* __restrict__ si1) {
    int i  = blockIdx.x;
    int sp = blockIdx.y;
    const float* g = sp ? fi : fe;
    float* out = sp ? fi1 : fe1;
    float zoa = sp ? (1.0f / 1836.0f) : -1.0f;
    float Ec = zoa * E[i];
    int t = threadIdx.x;
    int j0 = 4 * t;

    float4 f0v, rv;
    rhs4(g, i, j0, Ec, f0v, rv);
    float4 o;
    o.x = f0v.x + DTf * rv.x;
    o.y = f0v.y + DTf * rv.y;
    o.z = f0v.z + DTf * rv.z;
    o.w = f0v.w + DTf * rv.w;
    *(float4*)(out + i * NV + j0) = o;

    __shared__ float sred[4];
    float s = block_sum256(o.x + o.y + o.z + o.w, sred);
    if (t == 0) { (sp ? si1 : se1)[i] = s; }
}

// Stage 2 + implicit LBO collide, fused. One block (256 thr) per (row, sp).
// Stage values -> padded LDS; wave 0: per-lane 16-elem chunk elimination,
// 2x2-block PCR over 64 lanes (shuffles), direct coalesced global store.
__global__ __launch_bounds__(256) void stage2_collide_kernel(const float* __restrict__ fe,
                                                             const float* __restrict__ fi,
                                                             const float* __restrict__ fe1,
                                                             const float* __restrict__ fi1,
                                                             const float* __restrict__ E,
                                                             float* __restrict__ out) {
    const float Tdv2   = 1.0f / (DVf * DVf);
    const float inv2dv = 0.5f / DVf;

    int i  = blockIdx.x;
    int sp = blockIdx.y;
    const float* h = sp ? fi : fe;
    const float* g = sp ? fi1 : fe1;
    float* orow = out + ((size_t)sp * NX + i) * NV;
    float zoa = sp ? (1.0f / 1836.0f) : -1.0f;
    float lam = sp ? 0.1f : 1.0f;
    float Ec = zoa * E[i];
    int t = threadIdx.x;
    int lane = t & 63;
    int wave = t >> 6;

    __shared__ float lds_f[NV + NV / 16];   // padded: addr(j) = j + (j>>4)

    {
        int j0 = 4 * t;
        float4 f0v, rv;
        rhs4(g, i, j0, Ec, f0v, rv);
        float4 h4 = *(const float4*)(h + i * NV + j0);
        int a = j0 + (j0 >> 4);             // j0..j0+3 stay in one 16-group
        lds_f[a]     = 0.5f * h4.x + 0.5f * f0v.x + (0.5f * DTf) * rv.x;
        lds_f[a + 1] = 0.5f * h4.y + 0.5f * f0v.y + (0.5f * DTf) * rv.y;
        lds_f[a + 2] = 0.5f * h4.z + 0.5f * f0v.z + (0.5f * DTf) * rv.z;
        lds_f[a + 3] = 0.5f * h4.w + 0.5f * f0v.w + (0.5f * DTf) * rv.w;
    }
    __syncthreads();
    if (wave != 0) return;

    // row-constant collision coefficients
    float xi = DXf * ((float)i + 0.5f) - 0.5f;
    float nu = 1.0f / (1.0f + 0.5f * (expf(60.0f * xi - 20.0f) + expf(-60.0f * xi - 20.0f)));
    float K = DTf * nu * lam;
    float b = 1.0f + 2.0f * K * Tdv2;

    // per-lane chunk elimination: x_r = Dv_r - Av_r*z_left - Cv_r*y_right
    float Dv[16], Av[16], Cv[16];
    int j0 = lane * 16;
    int base = 17 * lane;
    #pragma unroll
    for (int r = 0; r < 16; ++r) {
        int j = j0 + r;
        float d = lds_f[base + r];
        float a = (j == 0)      ? 0.0f : -K * (Tdv2 - (DVf * ((float)j - 0.5f) - 6.0f) * inv2dv);
        float c = (j == NV - 1) ? 0.0f : -K * (Tdv2 + (DVf * ((float)j + 1.5f) - 6.0f) * inv2dv);
        if (r == 0) {
            float e = frcp(b);
            Dv[0] = e * d;
            Av[0] = e * a;
            Cv[0] = e * c;
        } else {
            float e = frcp(b - a * Cv[r - 1]);
            Dv[r] = e * (d - a * Dv[r - 1]);
            Av[r] = -e * a * Av[r - 1];
            Cv[r] = e * c;
        }
    }
    #pragma unroll
    for (int r = 14; r >= 0; --r) {
        Dv[r] = Dv[r] - Cv[r] * Dv[r + 1];
        Av[r] = Av[r] - Cv[r] * Av[r + 1];
        Cv[r] = -Cv[r] * Cv[r + 1];
    }

    // interface system per lane t: u_t + L_t u_{t-1} + R_t u_{t+1} = d_t
    //   u_t=(y_t,z_t)=(x_first,x_last); L col-z-only (la,lb); R col-y-only (ra,rb)
    float la = Av[0],  ra = Cv[0],  d0 = Dv[0];
    float lb = Av[15], rb = Cv[15], d1 = Dv[15];

    // PCR: 6 steps of distance 1,2,4,8,16,32
    #pragma unroll
    for (int s = 1; s < 64; s <<= 1) {
        float lb_m = __shfl_up(lb, s, 64);
        float rb_m = __shfl_up(rb, s, 64);
        float d1_m = __shfl_up(d1, s, 64);
        if (lane < s) { lb_m = 0.0f; rb_m = 0.0f; d1_m = 0.0f; }
        float la_p = __shfl_down(la, s, 64);
        float ra_p = __shfl_down(ra, s, 64);
        float d0_p = __shfl_down(d0, s, 64);
        if (lane + s > 63) { la_p = 0.0f; ra_p = 0.0f; d0_p = 0.0f; }

        float m00 = 1.0f - la * rb_m;
        float m01 = -ra * la_p;
        float m10 = -lb * rb_m;
        float m11 = 1.0f - rb * la_p;
        float idet = frcp(m00 * m11 - m01 * m10);

        float Lr0 = -la * lb_m, Lr1 = -lb * lb_m;
        float Rr0 = -ra * ra_p, Rr1 = -rb * ra_p;
        float e0 = d0 - la * d1_m - ra * d0_p;
        float e1 = d1 - lb * d1_m - rb * d0_p;

        la = idet * (m11 * Lr0 - m01 * Lr1);
        lb = idet * (m00 * Lr1 - m10 * Lr0);
        ra = idet * (m11 * Rr0 - m01 * Rr1);
        rb = idet * (m00 * Rr1 - m10 * Rr0);
        d0 = idet * (m11 * e0 - m01 * e1);
        d1 = idet * (m00 * e1 - m10 * e0);
    }
    // now u_t = (d0, d1)
    float zl = __shfl_up(d1, 1, 64);
    if (lane == 0) zl = 0.0f;
    float yr = __shfl_down(d0, 1, 64);
    if (lane == 63) yr = 0.0f;

    // reconstruct and store directly (lane owns 16 contiguous outputs)
    float x[16];
    #pragma unroll
    for (int r = 0; r < 16; ++r) x[r] = Dv[r] - Av[r] * zl - Cv[r] * yr;
    #pragma unroll
    for (int q = 0; q < 4; ++q) {
        float4 o;
        o.x = x[4 * q];
        o.y = x[4 * q + 1];
        o.z = x[4 * q + 2];
        o.w = x[4 * q + 3];
        *(float4*)(orow + j0 + 4 * q) = o;
    }
}

extern "C" void kernel_launch(void* const* d_in, const int* in_sizes, int n_in,
                              void* d_out, int out_size, void* d_ws, size_t ws_size,
                              hipStream_t stream) {
    const float* fe = (const float*)d_in[0];
    const float* fi = (const float*)d_in[1];
    float* out = (float*)d_out;
    const size_t P = (size_t)NX * NV;

    float* fe1 = (float*)d_ws;
    float* fi1 = fe1 + P;
    float* se  = fi1 + P;
    float* si  = se + NX;
    float* E   = si + NX;
    float* se1 = E + NX;
    float* si1 = se1 + NX;
    float* E1  = si1 + NX;

    dim3 rgrid(NX, 2);

    moments_kernel<<<NX, 256, 0, stream>>>(fe, fi, se, si);
    poisson_kernel<<<1, 1024, 0, stream>>>(se, si, E);
    stage1_kernel<<<rgrid, 256, 0, stream>>>(fe, fi, E, fe1, fi1, se1, si1);
    poisson_kernel<<<1, 1024, 0, stream>>>(se1, si1, E1);
    stage2_collide_kernel<<<rgrid, 256, 0, stream>>>(fe, fi, fe1, fi1, E1, out);
}

// Round 5
// 112.945 us; speedup vs baseline: 1.2676x; 1.0279x over previous
//
#include <hip/hip_runtime.h>
#include <math.h>

#define NX 2048
#define NV 1024
static constexpr float DXf   = 1.0f / 2048.0f;
static constexpr float DVf   = 12.0f / 1024.0f;
static constexpr float DTf   = 0.001f;
static constexpr float INV_DX = 2048.0f;
static constexpr float INV_DV = 1024.0f / 12.0f;

__device__ __forceinline__ float minmod_f(float a, float b) {
    return (a * b > 0.0f) ? (a > 0.0f ? fminf(a, b) : fmaxf(a, b)) : 0.0f;
}

__device__ __forceinline__ float frcp(float x) {
    float r = __builtin_amdgcn_rcpf(x);
    return r * (2.0f - x * r);
}

// Vectorized MUSCL rhs for 4 contiguous cells j0..j0+3 (j0 % 4 == 0).
__device__ __forceinline__ void rhs4(const float* __restrict__ g, int i, int j0, float Ec,
                                     float4& f0v, float4& rv) {
    const float* rowc = g + i * NV;
    const float* rm1  = g + (((i - 1) & (NX - 1)) * NV);
    const float* rm2  = g + (((i - 2) & (NX - 1)) * NV);
    const float* rp1  = g + (((i + 1) & (NX - 1)) * NV);
    const float* rp2  = g + (((i + 2) & (NX - 1)) * NV);

    float4 c   = *(const float4*)(rowc + j0);
    float4 xm1 = *(const float4*)(rm1 + j0);
    float4 xm2 = *(const float4*)(rm2 + j0);
    float4 xp1 = *(const float4*)(rp1 + j0);
    float4 xp2 = *(const float4*)(rp2 + j0);
    float4 lm = make_float4(0.f, 0.f, 0.f, 0.f);
    float4 rp = make_float4(0.f, 0.f, 0.f, 0.f);
    if (j0 >= 4)      lm = *(const float4*)(rowc + j0 - 4);
    if (j0 <= NV - 8) rp = *(const float4*)(rowc + j0 + 4);

    float vals[8] = {lm.z, lm.w, c.x, c.y, c.z, c.w, rp.x, rp.y};
    const float* cc   = (const float*)&c;
    const float* am1  = (const float*)&xm1;
    const float* am2  = (const float*)&xm2;
    const float* ap1  = (const float*)&xp1;
    const float* ap2  = (const float*)&xp2;
    float* f0o = (float*)&f0v;
    float* ro  = (float*)&rv;

    #pragma unroll
    for (int k = 0; k < 4; ++k) {
        float f0  = cc[k];
        float fm1 = am1[k], fm2 = am2[k], fp1 = ap1[k], fp2 = ap2[k];

        float v = DVf * ((float)(j0 + k) + 0.5f) - 6.0f;
        float dm1 = fm1 - fm2, d0 = f0 - fm1, dp1 = fp1 - f0, dp2 = fp2 - fp1;
        float sm1 = minmod_f(dm1, d0);
        float s0  = minmod_f(d0, dp1);
        float sp1 = minmod_f(dp1, dp2);
        float PhiM, PhiP;
        if (v > 0.0f) {
            PhiM = (fm1 + 0.5f * sm1) * v;
            PhiP = (f0  + 0.5f * s0 ) * v;
        } else {
            PhiM = (f0  - 0.5f * s0 ) * v;
            PhiP = (fp1 - 0.5f * sp1) * v;
        }
        float vdfdx = (PhiP - PhiM) * INV_DX;

        float gm2 = vals[k], gm1 = vals[k + 1], gp1 = vals[k + 3], gp2 = vals[k + 4];
        float em1 = gm1 - gm2, e0 = f0 - gm1, ep1 = gp1 - f0, ep2 = gp2 - gp1;
        float tm1 = minmod_f(em1, e0);
        float t0  = minmod_f(e0, ep1);
        float tp1 = minmod_f(ep1, ep2);
        float GM, GP;
        if (Ec > 0.0f) {
            GM = (gm1 + 0.5f * tm1) * Ec;
            GP = (f0  + 0.5f * t0 ) * Ec;
        } else {
            GM = (f0  - 0.5f * t0 ) * Ec;
            GP = (gp1 - 0.5f * tp1) * Ec;
        }
        float Edfdv = (GP - GM) * INV_DV;

        f0o[k] = f0;
        ro[k]  = -vdfdx - Edfdv;
    }
}

// E[i] = DX*(P_i - W/NX), P_i = sum_{k<=i} rho_k, W = sum_k rho_k*(NX-k).
// Identical to cumsum(rho)*DX - mean. All 256 threads return the value.
__device__ __forceinline__ float compute_E(const float* __restrict__ se,
                                           const float* __restrict__ si, int i) {
    int t = threadIdx.x;
    float pref = 0.0f, wtot = 0.0f;
    #pragma unroll
    for (int q = 0; q < NX / 256; ++q) {
        int k = q * 256 + t;
        float rho = DVf * (si[k] - se[k]);
        if (k <= i) pref += rho;
        wtot += rho * (float)(NX - k);
    }
    #pragma unroll
    for (int off = 32; off > 0; off >>= 1) {
        pref += __shfl_down(pref, off, 64);
        wtot += __shfl_down(wtot, off, 64);
    }
    __shared__ float sp[4], sw[4];
    int lane = t & 63, wave = t >> 6;
    if (lane == 0) { sp[wave] = pref; sw[wave] = wtot; }
    __syncthreads();
    float P = sp[0] + sp[1] + sp[2] + sp[3];
    float W = sw[0] + sw[1] + sw[2] + sw[3];
    return DXf * (P - W * (1.0f / (float)NX));
}

// se[i] = sum_j fe[i,j]; si[i] = sum_j fi[i,j]
__global__ __launch_bounds__(256) void moments_kernel(const float* __restrict__ fe,
                                                      const float* __restrict__ fi,
                                                      float* __restrict__ se,
                                                      float* __restrict__ si) {
    int i = blockIdx.x;
    int t = threadIdx.x;
    float4 a4 = *(const float4*)(fe + (size_t)i * NV + 4 * t);
    float4 b4 = *(const float4*)(fi + (size_t)i * NV + 4 * t);
    float a = a4.x + a4.y + a4.z + a4.w;
    float b = b4.x + b4.y + b4.z + b4.w;
    __shared__ float r1[4], r2[4];
    #pragma unroll
    for (int off = 32; off > 0; off >>= 1) {
        a += __shfl_down(a, off, 64);
        b += __shfl_down(b, off, 64);
    }
    int lane = t & 63, wave = t >> 6;
    if (lane == 0) { r1[wave] = a; r2[wave] = b; }
    __syncthreads();
    if (t == 0) {
        se[i] = r1[0] + r1[1] + r1[2] + r1[3];
        si[i] = r2[0] + r2[1] + r2[2] + r2[3];
    }
}

// Stage 1: f1 = f + dt*rhs(f); E computed in-block; writes row sums of f1.
__global__ __launch_bounds__(256) void stage1_kernel(const float* __restrict__ fe,
                                                     const float* __restrict__ fi,
                                                     const float* __restrict__ se,
                                                     const float* __restrict__ si,
                                                     float* __restrict__ fe1,
                                                     float* __restrict__ fi1,
                                                     float* __restrict__ se1,
                                                     float* __restrict__ si1) {
    int i  = blockIdx.x;
    int sp = blockIdx.y;
    const float* g = sp ? fi : fe;
    float* out = sp ? fi1 : fe1;
    float zoa = sp ? (1.0f / 1836.0f) : -1.0f;
    float Ec = zoa * compute_E(se, si, i);
    int t = threadIdx.x;
    int j0 = 4 * t;

    float4 f0v, rv;
    rhs4(g, i, j0, Ec, f0v, rv);
    float4 o;
    o.x = f0v.x + DTf * rv.x;
    o.y = f0v.y + DTf * rv.y;
    o.z = f0v.z + DTf * rv.z;
    o.w = f0v.w + DTf * rv.w;
    *(float4*)(out + i * NV + j0) = o;

    float x = o.x + o.y + o.z + o.w;
    #pragma unroll
    for (int off = 32; off > 0; off >>= 1) x += __shfl_down(x, off, 64);
    __shared__ float sred[4];
    int lane = t & 63, wave = t >> 6;
    if (lane == 0) sred[wave] = x;
    __syncthreads();
    if (t == 0) { (sp ? si1 : se1)[i] = sred[0] + sred[1] + sred[2] + sred[3]; }
}

// Stage 2 + implicit LBO collide, fused. One block (256 thr) per (row, sp).
__global__ __launch_bounds__(256) void stage2_collide_kernel(const float* __restrict__ fe,
                                                             const float* __restrict__ fi,
                                                             const float* __restrict__ fe1,
                                                             const float* __restrict__ fi1,
                                                             const float* __restrict__ se1,
                                                             const float* __restrict__ si1,
                                                             float* __restrict__ out) {
    const float Tdv2   = 1.0f / (DVf * DVf);
    const float inv2dv = 0.5f / DVf;

    int i  = blockIdx.x;
    int sp = blockIdx.y;
    const float* h = sp ? fi : fe;
    const float* g = sp ? fi1 : fe1;
    float* orow = out + ((size_t)sp * NX + i) * NV;
    float zoa = sp ? (1.0f / 1836.0f) : -1.0f;
    float lam = sp ? 0.1f : 1.0f;
    float Ec = zoa * compute_E(se1, si1, i);
    int t = threadIdx.x;
    int lane = t & 63;
    int wave = t >> 6;

    __shared__ float lds_f[NV + NV / 16];   // padded: addr(j) = j + (j>>4)

    {
        int j0 = 4 * t;
        float4 f0v, rv;
        rhs4(g, i, j0, Ec, f0v, rv);
        float4 h4 = *(const float4*)(h + i * NV + j0);
        int a = j0 + (j0 >> 4);
        lds_f[a]     = 0.5f * h4.x + 0.5f * f0v.x + (0.5f * DTf) * rv.x;
        lds_f[a + 1] = 0.5f * h4.y + 0.5f * f0v.y + (0.5f * DTf) * rv.y;
        lds_f[a + 2] = 0.5f * h4.z + 0.5f * f0v.z + (0.5f * DTf) * rv.z;
        lds_f[a + 3] = 0.5f * h4.w + 0.5f * f0v.w + (0.5f * DTf) * rv.w;
    }
    __syncthreads();
    if (wave != 0) return;

    float xi = DXf * ((float)i + 0.5f) - 0.5f;
    float nu = 1.0f / (1.0f + 0.5f * (expf(60.0f * xi - 20.0f) + expf(-60.0f * xi - 20.0f)));
    float K = DTf * nu * lam;
    float b = 1.0f + 2.0f * K * Tdv2;

    float Dv[16], Av[16], Cv[16];
    int j0 = lane * 16;
    int base = 17 * lane;
    #pragma unroll
    for (int r = 0; r < 16; ++r) {
        int j = j0 + r;
        float d = lds_f[base + r];
        float a = (j == 0)      ? 0.0f : -K * (Tdv2 - (DVf * ((float)j - 0.5f) - 6.0f) * inv2dv);
        float c = (j == NV - 1) ? 0.0f : -K * (Tdv2 + (DVf * ((float)j + 1.5f) - 6.0f) * inv2dv);
        if (r == 0) {
            float e = frcp(b);
            Dv[0] = e * d;
            Av[0] = e * a;
            Cv[0] = e * c;
        } else {
            float e = frcp(b - a * Cv[r - 1]);
            Dv[r] = e * (d - a * Dv[r - 1]);
            Av[r] = -e * a * Av[r - 1];
            Cv[r] = e * c;
        }
    }
    #pragma unroll
    for (int r = 14; r >= 0; --r) {
        Dv[r] = Dv[r] - Cv[r] * Dv[r + 1];
        Av[r] = Av[r] - Cv[r] * Av[r + 1];
        Cv[r] = -Cv[r] * Cv[r + 1];
    }

    // interface system per lane t: u_t + L_t u_{t-1} + R_t u_{t+1} = d_t
    float la = Av[0],  ra = Cv[0],  d0 = Dv[0];
    float lb = Av[15], rb = Cv[15], d1 = Dv[15];

    #pragma unroll
    for (int s = 1; s < 64; s <<= 1) {
        float lb_m = __shfl_up(lb, s, 64);
        float rb_m = __shfl_up(rb, s, 64);
        float d1_m = __shfl_up(d1, s, 64);
        if (lane < s) { lb_m = 0.0f; rb_m = 0.0f; d1_m = 0.0f; }
        float la_p = __shfl_down(la, s, 64);
        float ra_p = __shfl_down(ra, s, 64);
        float d0_p = __shfl_down(d0, s, 64);
        if (lane + s > 63) { la_p = 0.0f; ra_p = 0.0f; d0_p = 0.0f; }

        float m00 = 1.0f - la * rb_m;
        float m01 = -ra * la_p;
        float m10 = -lb * rb_m;
        float m11 = 1.0f - rb * la_p;
        float idet = frcp(m00 * m11 - m01 * m10);

        float Lr0 = -la * lb_m, Lr1 = -lb * lb_m;
        float Rr0 = -ra * ra_p, Rr1 = -rb * ra_p;
        float e0 = d0 - la * d1_m - ra * d0_p;
        float e1 = d1 - lb * d1_m - rb * d0_p;

        la = idet * (m11 * Lr0 - m01 * Lr1);
        lb = idet * (m00 * Lr1 - m10 * Lr0);
        ra = idet * (m11 * Rr0 - m01 * Rr1);
        rb = idet * (m00 * Rr1 - m10 * Rr0);
        d0 = idet * (m11 * e0 - m01 * e1);
        d1 = idet * (m00 * e1 - m10 * e0);
    }
    float zl = __shfl_up(d1, 1, 64);
    if (lane == 0) zl = 0.0f;
    float yr = __shfl_down(d0, 1, 64);
    if (lane == 63) yr = 0.0f;

    float x[16];
    #pragma unroll
    for (int r = 0; r < 16; ++r) x[r] = Dv[r] - Av[r] * zl - Cv[r] * yr;
    #pragma unroll
    for (int q = 0; q < 4; ++q) {
        float4 o;
        o.x = x[4 * q];
        o.y = x[4 * q + 1];
        o.z = x[4 * q + 2];
        o.w = x[4 * q + 3];
        *(float4*)(orow + j0 + 4 * q) = o;
    }
}

extern "C" void kernel_launch(void* const* d_in, const int* in_sizes, int n_in,
                              void* d_out, int out_size, void* d_ws, size_t ws_size,
                              hipStream_t stream) {
    const float* fe = (const float*)d_in[0];
    const float* fi = (const float*)d_in[1];
    float* out = (float*)d_out;
    const size_t P = (size_t)NX * NV;

    float* fe1 = (float*)d_ws;
    float* fi1 = fe1 + P;
    float* se  = fi1 + P;
    float* si  = se + NX;
    float* se1 = si + NX;
    float* si1 = se1 + NX;

    dim3 rgrid(NX, 2);

    moments_kernel<<<NX, 256, 0, stream>>>(fe, fi, se, si);
    stage1_kernel<<<rgrid, 256, 0, stream>>>(fe, fi, se, si, fe1, fi1, se1, si1);
    stage2_collide_kernel<<<rgrid, 256, 0, stream>>>(fe, fi, fe1, fi1, se1, si1, out);
}